// Round 6
// baseline (162.873 us; speedup 1.0000x reference)
//
#include <hip/hip_runtime.h>
#include <math.h>

#define NF 15552      // B*T
#define NJ 17
#define NC 128
#define JC (NJ*NC)    // 2176
#define TT 243        // frames per batch
#define FB 4          // frames per iteration
#define NIT 8         // iterations per block
#define FRB (FB*NIT)  // 32 frames per block; grid = NF/FRB = 486

constexpr int cA[15] = {0,1,2,0,4,5,0,7,8,0,10,11,0,13,14};
constexpr int cB[15] = {1,2,3,4,5,6,7,8,9,10,11,12,13,14,15};
constexpr int aJ[4] = {11,14,5,8};
constexpr int aP[4] = {10,13,4,7};
constexpr int aCc[4] = {12,15,6,9};

__device__ const int d_cA16[16] = {0,1,2,0,4,5,0,7,8,0,10,11,0,13,14,0};
__device__ const int d_cB16[16] = {1,2,3,4,5,6,7,8,9,10,11,12,13,14,15,0};

typedef __bf16 bf16x8 __attribute__((ext_vector_type(8)));
typedef float f32x4 __attribute__((ext_vector_type(4)));
typedef unsigned short u16x8 __attribute__((ext_vector_type(8)));

__device__ __forceinline__ float gelu_exact(float x){
  return 0.5f * x * (1.0f + erff(x * 0.7071067811865476f));
}
// tanh-form gelu; |err vs exact| <= ~3e-3
__device__ __forceinline__ float gelu_fast(float x){
  const float s2 = x * x;
  const float q  = fmaf(s2, -0.1029437f, -2.3021183f);
  const float e  = __builtin_amdgcn_exp2f(q * x);
  return x * __builtin_amdgcn_rcpf(1.0f + e);
}
__device__ __forceinline__ unsigned short bfc(float x){
  return __builtin_bit_cast(unsigned short, (__bf16)x);
}
__device__ __forceinline__ float bf2f(unsigned short u){
  return __builtin_bit_cast(float, ((unsigned)u) << 16);
}

// ---------------- geometry + mean_acc zeroing ----------------
__global__ __launch_bounds__(256) void k_geom(const float* __restrict__ pose,
                                              float* __restrict__ out_aa,
                                              float* __restrict__ out_abl,
                                              float* __restrict__ mean_acc)
{
  for (long i = (long)blockIdx.x*256 + threadIdx.x; i < 64L*JC; i += (long)gridDim.x*256)
    mean_acc[i] = 0.0f;

  const int f = blockIdx.x * 256 + threadIdx.x;
  if (f >= NF) return;
  const float* p = pose + (long)f * NJ * 3;
  float px[NJ], py[NJ], pz[NJ];
  #pragma unroll
  for (int j = 0; j < NJ; ++j){ px[j] = p[3*j]; py[j] = p[3*j+1]; pz[j] = p[3*j+2]; }

  #pragma unroll
  for (int i = 0; i < 15; ++i){
    const int a = cA[i], b = cB[i];
    const float dx = px[b]-px[a], dy = py[b]-py[a], dz = pz[b]-pz[a];
    out_abl[(long)f*15 + i] = sqrtf(dx*dx + dy*dy + dz*dz);
  }

  float ang[NJ];
  #pragma unroll
  for (int j = 0; j < NJ; ++j) ang[j] = 0.0f;
  #pragma unroll
  for (int i = 0; i < 4; ++i){
    const int jj = aJ[i], pp = aP[i], cc = aCc[i];
    float v1x = px[jj]-px[pp], v1y = py[jj]-py[pp], v1z = pz[jj]-pz[pp];
    float v2x = px[cc]-px[jj], v2y = py[cc]-py[jj], v2z = pz[cc]-pz[jj];
    const float n1 = sqrtf(v1x*v1x + v1y*v1y + v1z*v1z) + 1e-10f;
    const float n2 = sqrtf(v2x*v2x + v2y*v2y + v2z*v2z) + 1e-10f;
    v1x /= n1; v1y /= n1; v1z /= n1;
    v2x /= n2; v2y /= n2; v2z /= n2;
    float d = v1x*v2x + v1y*v2y + v1z*v2z;
    d = fminf(fmaxf(d, -1.0f + 1e-7f), 1.0f - 1e-7f);
    ang[jj] = acosf(d);
  }
  #pragma unroll
  for (int j = 0; j < NJ; ++j) out_aa[(long)f*NJ + j] = ang[j];
}

// ---------------- fused: angle MLP + bone MLP + mean partial ----------------
// LDS: double-buffered FB frames x 17 x 128 bf16, 16B blocks swizzled kb^(j&7).
// T14 schedule per iter: [bar] issue-loads(it+1) | MFMA+epilogues+mean | [bar]
//                        bone-reduce | vmcnt-wait+cvt+ds_write(it+1)
#define SFO(fi, off16) (((fi)*272 + (off16))*8)
#define NST 5   // staging units per thread: ceil(FB*272/256)

__global__ __launch_bounds__(256) void k_fused(const float* __restrict__ feat,
    const float* __restrict__ aw1, const float* __restrict__ ab1,
    const float* __restrict__ aw2, const float* __restrict__ ab2,
    const float* __restrict__ bw1, const float* __restrict__ bb1,
    const float* __restrict__ bw2, const float* __restrict__ bb2,
    float* __restrict__ out_pa, float* __restrict__ out_pbl,
    float* __restrict__ mean_acc)
{
  __shared__ __align__(16) unsigned short s_feat[2][FB*NJ*NC];  // 2x17408 B
  __shared__ float s_red[4][FB][16];                            // 1 KB

  const int tid  = threadIdx.x;
  const int w    = tid >> 6;
  const int lane = tid & 63;
  const int g    = lane >> 4;       // k-group
  const int c    = lane & 15;       // A-row / B,D-col within fragment
  const long F0  = (long)blockIdx.x * FRB;

  // ---- per-thread staging unit constants (same every iteration) ----
  bool uok[NST];
  int  woff[NST];
  #pragma unroll
  for (int s5 = 0; s5 < NST; ++s5){
    const int u = tid + 256*s5;
    uok[s5] = (u < FB*272);
    const int fi = u / 272, r = u - fi*272;
    const int j = r >> 4, kb = r & 15;
    woff[s5] = SFO(fi, j*16 + (kb ^ (j & 7)));
  }

  // ---- prologue: stage iteration 0 (load+wait+write) ----
  {
    const float* nb = feat + F0 * JC;
    unsigned short* dst = s_feat[0];
    #pragma unroll
    for (int s5 = 0; s5 < NST; ++s5) if (uok[s5]){
      const float4 v0 = *(const float4*)(nb + (tid + 256*s5)*8);
      const float4 v1 = *(const float4*)(nb + (tid + 256*s5)*8 + 4);
      u16x8 p;
      p[0]=bfc(v0.x); p[1]=bfc(v0.y); p[2]=bfc(v0.z); p[3]=bfc(v0.w);
      p[4]=bfc(v1.x); p[5]=bfc(v1.y); p[6]=bfc(v1.z); p[7]=bfc(v1.w);
      *(u16x8*)&dst[woff[s5]] = p;
    }
  }

  // ---- bone weight fragments (bw1 [256][128]) ----
  bf16x8 wb[8][2];
  float bb1c[2], bw2c[2];
  #pragma unroll
  for (int nf = 0; nf < 2; ++nf){
    const int col = w*32 + nf*16 + c;
    bb1c[nf] = bb1[col];
    bw2c[nf] = bw2[col];
    #pragma unroll
    for (int ks = 0; ks < 8; ++ks){
      u16x8 t;
      #pragma unroll
      for (int e = 0; e < 8; ++e) t[e] = bfc(bw1[(ks*32 + g*8 + e)*128 + col]);
      wb[ks][nf] = __builtin_bit_cast(bf16x8, t);
    }
  }
  // ---- angle weight fragments (aw1 [128][64]) ----
  bf16x8 wa[4][4];
  float ab1c[4], aw2c[4][3];
  #pragma unroll
  for (int nf = 0; nf < 4; ++nf){
    const int col = nf*16 + c;
    ab1c[nf] = ab1[col];
    #pragma unroll
    for (int m = 0; m < 3; ++m) aw2c[nf][m] = aw2[col*3 + m];
    #pragma unroll
    for (int kt = 0; kt < 4; ++kt){
      u16x8 t;
      #pragma unroll
      for (int e = 0; e < 8; ++e) t[e] = bfc(aw1[(kt*32 + g*8 + e)*64 + col]);
      wa[kt][nf] = __builtin_bit_cast(bf16x8, t);
    }
  }
  const float ab2c[3] = {ab2[0], ab2[1], ab2[2]};
  const float bb2c = bb2[0];

  // ---- bone A-fragment block offsets (swizzled) ----
  const int jA = d_cA16[c], jB = d_cB16[c];
  int boff[8];
  #pragma unroll
  for (int ks = 0; ks < 8; ++ks){
    const int kk = ks*32 + g*8;
    const int j  = (kk < 128) ? jA : jB;
    const int kb = (kk < 128) ? (ks*4 + g) : (ks*4 + g - 16);
    boff[ks] = j*16 + (kb ^ (j & 7));
  }

  // ---- mean accumulators (batch-split) ----
  const int b0    = (int)(F0 / TT);
  const int split = min(FRB, TT - (int)(F0 - (long)b0*TT));
  float m0[9], m1[9];
  #pragma unroll
  for (int s = 0; s < 9; ++s){ m0[s] = 0.f; m1[s] = 0.f; }

  int buf = 0;
  for (int it = 0; it < NIT; ++it){
    __syncthreads();                       // staged buf ready; s_red free

    // ---- T14 issue phase: global loads for it+1 into registers ----
    float4 rv0[NST], rv1[NST];
    if (it + 1 < NIT){
      const float* nb = feat + (F0 + (long)(it+1)*FB) * JC;
      #pragma unroll
      for (int s5 = 0; s5 < NST; ++s5) if (uok[s5]){
        rv0[s5] = *(const float4*)(nb + (tid + 256*s5)*8);
        rv1[s5] = *(const float4*)(nb + (tid + 256*s5)*8 + 4);
      }
      __builtin_amdgcn_sched_barrier(0);   // keep loads issued before compute
    }

    const unsigned short* fb = s_feat[buf];

    // ---- bone MFMA: all FB frames, this wave's 32 cols ----
    f32x4 bacc[FB][2];
    #pragma unroll
    for (int fi = 0; fi < FB; ++fi){ bacc[fi][0] = (f32x4)0.0f; bacc[fi][1] = (f32x4)0.0f; }
    #pragma unroll
    for (int ks = 0; ks < 8; ++ks){
      bf16x8 av[FB];
      #pragma unroll
      for (int fi = 0; fi < FB; ++fi)
        av[fi] = __builtin_bit_cast(bf16x8, *(const u16x8*)&fb[SFO(fi, boff[ks])]);
      #pragma unroll
      for (int fi = 0; fi < FB; ++fi){
        bacc[fi][0] = __builtin_amdgcn_mfma_f32_16x16x32_bf16(av[fi], wb[ks][0], bacc[fi][0], 0, 0, 0);
        bacc[fi][1] = __builtin_amdgcn_mfma_f32_16x16x32_bf16(av[fi], wb[ks][1], bacc[fi][1], 0, 0, 0);
      }
    }
    #pragma unroll
    for (int fi = 0; fi < FB; ++fi){
      float s[4] = {0.f, 0.f, 0.f, 0.f};
      #pragma unroll
      for (int nf = 0; nf < 2; ++nf)
        #pragma unroll
        for (int r = 0; r < 4; ++r)
          s[r] += gelu_fast(bacc[fi][nf][r] + bb1c[nf]) * bw2c[nf];
      #pragma unroll
      for (int r = 0; r < 4; ++r){
        s[r] += __shfl_xor(s[r], 1);
        s[r] += __shfl_xor(s[r], 2);
        s[r] += __shfl_xor(s[r], 4);
        s[r] += __shfl_xor(s[r], 8);
      }
      if (c == 0)
        #pragma unroll
        for (int r = 0; r < 4; ++r) s_red[w][fi][g*4 + r] = s[r];
    }

    // ---- angle MFMA: wave w -> frame w (16 joints); w0 also joint-16 rows ----
    f32x4 acc0[4], accj[4];
    #pragma unroll
    for (int nf = 0; nf < 4; ++nf){ acc0[nf]=(f32x4)0.0f; accj[nf]=(f32x4)0.0f; }
    #pragma unroll
    for (int kt = 0; kt < 4; ++kt){
      const int kbx = kt*4 + g;
      const bf16x8 av0 = __builtin_bit_cast(bf16x8,
          *(const u16x8*)&fb[SFO(w, c*16 + (kbx ^ (c & 7)))]);
      #pragma unroll
      for (int nf = 0; nf < 4; ++nf)
        acc0[nf] = __builtin_amdgcn_mfma_f32_16x16x32_bf16(av0, wa[kt][nf], acc0[nf], 0, 0, 0);
      if (w == 0){
        const bf16x8 avj = __builtin_bit_cast(bf16x8,
            *(const u16x8*)&fb[SFO(c & 3, 16*16 + kbx)]);   // joint 16 (j&7==0)
        #pragma unroll
        for (int nf = 0; nf < 4; ++nf)
          accj[nf] = __builtin_amdgcn_mfma_f32_16x16x32_bf16(avj, wa[kt][nf], accj[nf], 0, 0, 0);
      }
    }
    {
      float s[4][3];
      #pragma unroll
      for (int r = 0; r < 4; ++r){ s[r][0]=0.f; s[r][1]=0.f; s[r][2]=0.f; }
      #pragma unroll
      for (int nf = 0; nf < 4; ++nf)
        #pragma unroll
        for (int r = 0; r < 4; ++r){
          const float h = gelu_fast(acc0[nf][r] + ab1c[nf]);
          s[r][0] = fmaf(h, aw2c[nf][0], s[r][0]);
          s[r][1] = fmaf(h, aw2c[nf][1], s[r][1]);
          s[r][2] = fmaf(h, aw2c[nf][2], s[r][2]);
        }
      #pragma unroll
      for (int r = 0; r < 4; ++r)
        #pragma unroll
        for (int m = 0; m < 3; ++m){
          float v = s[r][m];
          v += __shfl_xor(v, 1);
          v += __shfl_xor(v, 2);
          v += __shfl_xor(v, 4);
          v += __shfl_xor(v, 8);
          s[r][m] = v;
        }
      if (c == 0){
        const long frame = F0 + (long)it*FB + w;
        #pragma unroll
        for (int r = 0; r < 4; ++r){
          const int joint = g*4 + r;
          #pragma unroll
          for (int m = 0; m < 3; ++m)
            out_pa[(frame*NJ + joint)*3 + m] = s[r][m] + ab2c[m];
        }
      }
    }
    if (w == 0){
      float s[4][3];
      #pragma unroll
      for (int r = 0; r < 4; ++r){ s[r][0]=0.f; s[r][1]=0.f; s[r][2]=0.f; }
      #pragma unroll
      for (int nf = 0; nf < 4; ++nf)
        #pragma unroll
        for (int r = 0; r < 4; ++r){
          const float h = gelu_fast(accj[nf][r] + ab1c[nf]);
          s[r][0] = fmaf(h, aw2c[nf][0], s[r][0]);
          s[r][1] = fmaf(h, aw2c[nf][1], s[r][1]);
          s[r][2] = fmaf(h, aw2c[nf][2], s[r][2]);
        }
      #pragma unroll
      for (int r = 0; r < 4; ++r)
        #pragma unroll
        for (int m = 0; m < 3; ++m){
          float v = s[r][m];
          v += __shfl_xor(v, 1);
          v += __shfl_xor(v, 2);
          v += __shfl_xor(v, 4);
          v += __shfl_xor(v, 8);
          s[r][m] = v;
        }
      if (c == 0 && g == 0){
        #pragma unroll
        for (int r = 0; r < 4; ++r){     // r = frame within iter
          const long frame = F0 + (long)it*FB + r;
          #pragma unroll
          for (int m = 0; m < 3; ++m)
            out_pa[(frame*NJ + 16)*3 + m] = s[r][m] + ab2c[m];
        }
      }
    }

    // ---- mean accumulate from staged tile ----
    #pragma unroll
    for (int s = 0; s < 9; ++s){
      const int jc = tid + s*256;
      if (jc < JC){
        const int j = jc >> 7, k = jc & 127;
        const int eoff = (j*16 + ((k >> 3) ^ (j & 7)))*8 + (k & 7);
        #pragma unroll
        for (int fi = 0; fi < FB; ++fi){
          const float v = bf2f(fb[fi*JC + eoff]);
          if (it*FB + fi < split) m0[s] += v; else m1[s] += v;
        }
      }
    }

    __syncthreads();                     // s_red complete; all reads of buf done
    if (tid < FB*15){
      const int fi = tid / 15, row = tid - fi*15;
      const float v = s_red[0][fi][row] + s_red[1][fi][row] +
                      s_red[2][fi][row] + s_red[3][fi][row] + bb2c;
      out_pbl[(F0 + (long)it*FB + fi)*15 + row] = fmaxf(v, 0.0f);
    }

    // ---- T14 write phase: cvt staged registers -> buf^1 ----
    if (it + 1 < NIT){
      unsigned short* dst = s_feat[buf ^ 1];
      #pragma unroll
      for (int s5 = 0; s5 < NST; ++s5) if (uok[s5]){
        u16x8 p;
        p[0]=bfc(rv0[s5].x); p[1]=bfc(rv0[s5].y); p[2]=bfc(rv0[s5].z); p[3]=bfc(rv0[s5].w);
        p[4]=bfc(rv1[s5].x); p[5]=bfc(rv1[s5].y); p[6]=bfc(rv1[s5].z); p[7]=bfc(rv1[s5].w);
        *(u16x8*)&dst[woff[s5]] = p;
      }
    }
    buf ^= 1;
  }

  // ---- mean flush: one atomic per (batch, jc) ----
  #pragma unroll
  for (int s = 0; s < 9; ++s){
    const int jc = tid + s*256;
    if (jc < JC){
      atomicAdd(&mean_acc[(long)b0*JC + jc], m0[s]);
      if (split < FRB) atomicAdd(&mean_acc[(long)(b0+1)*JC + jc], m1[s]);
    }
  }
}

// ---------------- action classifier (reads per-batch sums) ----------------
__global__ __launch_bounds__(256) void k_action(const float* __restrict__ sum_src,
    const float* __restrict__ cw1, const float* __restrict__ cb1,
    const float* __restrict__ cw2, const float* __restrict__ cb2,
    float* __restrict__ out_lg)
{
  __shared__ float s_m[JC];
  __shared__ float s_part[4][64];
  __shared__ float s_h[64];
  const int b = blockIdx.x, tid = threadIdx.x;
  for (int i = tid; i < JC; i += 256) s_m[i] = sum_src[(long)b*JC + i] * (1.0f/243.0f);
  __syncthreads();
  const int n = tid & 63, part = tid >> 6;
  float s = 0.0f;
  const int k0 = part * 544;
  for (int k = k0; k < k0 + 544; ++k) s = fmaf(s_m[k], cw1[(long)k*64 + n], s);
  s_part[part][n] = s;
  __syncthreads();
  if (tid < 64) s_h[tid] = gelu_exact(s_part[0][tid] + s_part[1][tid] +
                                      s_part[2][tid] + s_part[3][tid] + cb1[tid]);
  __syncthreads();
  if (tid < 8){
    float v = cb2[tid];
    #pragma unroll
    for (int k = 0; k < 64; ++k) v = fmaf(s_h[k], cw2[k*8 + tid], v);
    out_lg[b*8 + tid] = v;
  }
}

extern "C" void kernel_launch(void* const* d_in, const int* in_sizes, int n_in,
                              void* d_out, int out_size, void* d_ws, size_t ws_size,
                              hipStream_t stream)
{
  const float* feat = (const float*)d_in[0];
  const float* pose = (const float*)d_in[1];
  const float* aw1  = (const float*)d_in[2];
  const float* ab1  = (const float*)d_in[3];
  const float* aw2  = (const float*)d_in[4];
  const float* ab2  = (const float*)d_in[5];
  const float* bw1  = (const float*)d_in[6];
  const float* bb1  = (const float*)d_in[7];
  const float* bw2  = (const float*)d_in[8];
  const float* bb2  = (const float*)d_in[9];
  const float* cw1  = (const float*)d_in[10];
  const float* cb1  = (const float*)d_in[11];
  const float* cw2  = (const float*)d_in[12];
  const float* cb2  = (const float*)d_in[13];

  float* out = (float*)d_out;
  float* out_pa  = out;                 // [NF,17,3]  793152
  float* out_aa  = out + 793152;        // [NF,17,1]  264384
  float* out_pbl = out + 1057536;       // [NF,15,1]  233280
  float* out_abl = out + 1290816;       // [NF,15,1]  233280
  float* out_lg  = out + 1524096;       // [64,8]     512

  float* mean_acc = (float*)d_ws;       // 64*JC f32

  k_geom<<<dim3((NF + 255)/256), dim3(256), 0, stream>>>(pose, out_aa, out_abl, mean_acc);
  k_fused<<<dim3(NF/FRB), dim3(256), 0, stream>>>(feat, aw1, ab1, aw2, ab2,
                                                  bw1, bb1, bw2, bb2,
                                                  out_pa, out_pbl, mean_acc);
  k_action<<<dim3(64), dim3(256), 0, stream>>>(mean_acc, cw1, cb1, cw2, cb2, out_lg);
}

// Round 7
// 161.157 us; speedup vs baseline: 1.0106x; 1.0106x over previous
//
#include <hip/hip_runtime.h>
#include <math.h>

#define NF 15552      // B*T
#define NJ 17
#define NC 128
#define JC (NJ*NC)    // 2176
#define TT 243        // frames per batch
#define FB 4          // frames per iteration
#define NIT 8         // iterations per block
#define FRB (FB*NIT)  // 32 frames per block; grid = 486

constexpr int cA[15] = {0,1,2,0,4,5,0,7,8,0,10,11,0,13,14};
constexpr int cB[15] = {1,2,3,4,5,6,7,8,9,10,11,12,13,14,15};
constexpr int aJ[4] = {11,14,5,8};
constexpr int aP[4] = {10,13,4,7};
constexpr int aCc[4] = {12,15,6,9};

__device__ const int d_cA16[16] = {0,1,2,0,4,5,0,7,8,0,10,11,0,13,14,0};
__device__ const int d_cB16[16] = {1,2,3,4,5,6,7,8,9,10,11,12,13,14,15,0};

typedef __bf16 bf16x8 __attribute__((ext_vector_type(8)));
typedef float f32x4 __attribute__((ext_vector_type(4)));
typedef unsigned short u16x8 __attribute__((ext_vector_type(8)));

__device__ __forceinline__ float gelu_exact(float x){
  return 0.5f * x * (1.0f + erff(x * 0.7071067811865476f));
}
// tanh-form gelu; |err vs exact| <= ~3e-3
__device__ __forceinline__ float gelu_fast(float x){
  const float s2 = x * x;
  const float q  = fmaf(s2, -0.1029437f, -2.3021183f);
  const float e  = __builtin_amdgcn_exp2f(q * x);
  return x * __builtin_amdgcn_rcpf(1.0f + e);
}
__device__ __forceinline__ unsigned short bfc(float x){
  return __builtin_bit_cast(unsigned short, (__bf16)x);
}

// ---------------- geometry + mean_acc zeroing ----------------
__global__ __launch_bounds__(256) void k_geom(const float* __restrict__ pose,
                                              float* __restrict__ out_aa,
                                              float* __restrict__ out_abl,
                                              float* __restrict__ mean_acc)
{
  for (long i = (long)blockIdx.x*256 + threadIdx.x; i < 64L*JC; i += (long)gridDim.x*256)
    mean_acc[i] = 0.0f;

  const int f = blockIdx.x * 256 + threadIdx.x;
  if (f >= NF) return;
  const float* p = pose + (long)f * NJ * 3;
  float px[NJ], py[NJ], pz[NJ];
  #pragma unroll
  for (int j = 0; j < NJ; ++j){ px[j] = p[3*j]; py[j] = p[3*j+1]; pz[j] = p[3*j+2]; }

  #pragma unroll
  for (int i = 0; i < 15; ++i){
    const int a = cA[i], b = cB[i];
    const float dx = px[b]-px[a], dy = py[b]-py[a], dz = pz[b]-pz[a];
    out_abl[(long)f*15 + i] = sqrtf(dx*dx + dy*dy + dz*dz);
  }

  float ang[NJ];
  #pragma unroll
  for (int j = 0; j < NJ; ++j) ang[j] = 0.0f;
  #pragma unroll
  for (int i = 0; i < 4; ++i){
    const int jj = aJ[i], pp = aP[i], cc = aCc[i];
    float v1x = px[jj]-px[pp], v1y = py[jj]-py[pp], v1z = pz[jj]-pz[pp];
    float v2x = px[cc]-px[jj], v2y = py[cc]-py[jj], v2z = pz[cc]-pz[jj];
    const float n1 = sqrtf(v1x*v1x + v1y*v1y + v1z*v1z) + 1e-10f;
    const float n2 = sqrtf(v2x*v2x + v2y*v2y + v2z*v2z) + 1e-10f;
    v1x /= n1; v1y /= n1; v1z /= n1;
    v2x /= n2; v2y /= n2; v2z /= n2;
    float d = v1x*v2x + v1y*v2y + v1z*v2z;
    d = fminf(fmaxf(d, -1.0f + 1e-7f), 1.0f - 1e-7f);
    ang[jj] = acosf(d);
  }
  #pragma unroll
  for (int j = 0; j < NJ; ++j) out_aa[(long)f*NJ + j] = ang[j];
}

// ---------------- fused: angle MLP + bone MLP + mean (in staging) ----------------
// feat LDS: double-buffered FB frames x 17 x 128 bf16, 16B-unit swizzle kb^(j&7).
// wa LDS: aw1 transposed [col][k] bf16, unit swizzle kb^(col&7).
// One barrier per iteration; s_red double-buffered.
__global__ __launch_bounds__(256, 3) void k_fused(const float* __restrict__ feat,
    const float* __restrict__ aw1, const float* __restrict__ ab1,
    const float* __restrict__ aw2, const float* __restrict__ ab2,
    const float* __restrict__ bw1, const float* __restrict__ bb1,
    const float* __restrict__ bw2, const float* __restrict__ bb2,
    float* __restrict__ out_pa, float* __restrict__ out_pbl,
    float* __restrict__ mean_acc)
{
  __shared__ __align__(16) unsigned short s_feat[2][FB*JC];   // 34816 B
  __shared__ __align__(16) unsigned short s_wa[64*128];       // 16384 B
  __shared__ float s_red[2][4][FB][16];                       // 2048 B

  const int tid  = threadIdx.x;
  const int w    = tid >> 6;
  const int lane = tid & 63;
  const int g    = lane >> 4;       // k-group
  const int c    = lane & 15;       // A-row / B,D-col within fragment
  const long F0  = (long)blockIdx.x * FRB;

  // ---- mean bookkeeping: thread owns (jm, kbm*8..+7); tail threads own j16 ----
  const int jm  = tid >> 4, kbm = tid & 15;
  const int woffm = (jm*16 + (kbm ^ (jm & 7)))*8;   // u16 offset within a frame
  const bool xtr = (tid >= 240);
  const int kx = tid & 15;
  const int b0 = (int)(F0 / TT);
  const long bsplit = (long)(b0 + 1) * TT;
  int curb = b0;
  float mm[8], mx[8];
  #pragma unroll
  for (int e = 0; e < 8; ++e){ mm[e] = 0.f; mx[e] = 0.f; }

  auto flushMean = [&](int batch){
    #pragma unroll
    for (int e = 0; e < 8; ++e)
      atomicAdd(&mean_acc[(long)batch*JC + jm*128 + kbm*8 + e], mm[e]);
    if (xtr){
      #pragma unroll
      for (int e = 0; e < 8; ++e)
        atomicAdd(&mean_acc[(long)batch*JC + 2048 + kx*8 + e], mx[e]);
    }
    #pragma unroll
    for (int e = 0; e < 8; ++e){ mm[e] = 0.f; mx[e] = 0.f; }
  };

  // ---- staging: f32 global -> bf16 swizzled LDS + f32 mean accumulate ----
  auto stage = [&](int bsel, int it){
    const long fbase = F0 + (long)it*FB;
    const float* base = feat + fbase*JC;
    unsigned short* dst = s_feat[bsel];
    #pragma unroll
    for (int fi = 0; fi < FB; ++fi){
      if (fbase + fi == bsplit){ flushMean(b0); curb = b0 + 1; }  // uniform, rare
      const float* p = base + fi*JC + jm*128 + kbm*8;
      const float4 v0 = *(const float4*)p;
      const float4 v1 = *(const float4*)(p + 4);
      mm[0]+=v0.x; mm[1]+=v0.y; mm[2]+=v0.z; mm[3]+=v0.w;
      mm[4]+=v1.x; mm[5]+=v1.y; mm[6]+=v1.z; mm[7]+=v1.w;
      u16x8 q;
      q[0]=bfc(v0.x); q[1]=bfc(v0.y); q[2]=bfc(v0.z); q[3]=bfc(v0.w);
      q[4]=bfc(v1.x); q[5]=bfc(v1.y); q[6]=bfc(v1.z); q[7]=bfc(v1.w);
      *(u16x8*)&dst[fi*JC + woffm] = q;
      if (xtr){
        const float* px = base + fi*JC + 2048 + kx*8;
        const float4 x0 = *(const float4*)px;
        const float4 x1 = *(const float4*)(px + 4);
        mx[0]+=x0.x; mx[1]+=x0.y; mx[2]+=x0.z; mx[3]+=x0.w;
        mx[4]+=x1.x; mx[5]+=x1.y; mx[6]+=x1.z; mx[7]+=x1.w;
        u16x8 qx;
        qx[0]=bfc(x0.x); qx[1]=bfc(x0.y); qx[2]=bfc(x0.z); qx[3]=bfc(x0.w);
        qx[4]=bfc(x1.x); qx[5]=bfc(x1.y); qx[6]=bfc(x1.z); qx[7]=bfc(x1.w);
        *(u16x8*)&dst[fi*JC + (256 + kx)*8] = qx;
      }
    }
  };

  // ---- stage aw1 transposed+swizzled into LDS (once) ----
  {
    #pragma unroll
    for (int s = 0; s < 4; ++s){
      const int U = tid + 256*s;        // 1024 units: col=U>>4, kb=U&15
      const int col = U >> 4, kb = U & 15;
      u16x8 t;
      #pragma unroll
      for (int e = 0; e < 8; ++e) t[e] = bfc(aw1[(kb*8 + e)*64 + col]);
      *(u16x8*)&s_wa[(col*16 + (kb ^ (col & 7)))*8] = t;
    }
  }

  stage(0, 0);

  // ---- bone weight fragments (bw1 [256][128]) in registers ----
  bf16x8 wb[8][2];
  float bb1c[2], bw2c[2];
  #pragma unroll
  for (int nf = 0; nf < 2; ++nf){
    const int col = w*32 + nf*16 + c;
    bb1c[nf] = bb1[col];
    bw2c[nf] = bw2[col];
    #pragma unroll
    for (int ks = 0; ks < 8; ++ks){
      u16x8 t;
      #pragma unroll
      for (int e = 0; e < 8; ++e) t[e] = bfc(bw1[(ks*32 + g*8 + e)*128 + col]);
      wb[ks][nf] = __builtin_bit_cast(bf16x8, t);
    }
  }
  // ---- small epilogue constants ----
  float ab1c[4], aw2c[4][3];
  #pragma unroll
  for (int nf = 0; nf < 4; ++nf){
    const int col = nf*16 + c;
    ab1c[nf] = ab1[col];
    #pragma unroll
    for (int m = 0; m < 3; ++m) aw2c[nf][m] = aw2[col*3 + m];
  }
  const float ab2c[3] = {ab2[0], ab2[1], ab2[2]};
  const float bb2c = bb2[0];

  // ---- bone A-fragment unit offsets (swizzled) ----
  const int jA = d_cA16[c], jB = d_cB16[c];
  int boff[8];
  #pragma unroll
  for (int ks = 0; ks < 8; ++ks){
    const int kk = ks*32 + g*8;
    const int j  = (kk < 128) ? jA : jB;
    const int kb = (kk < 128) ? (ks*4 + g) : (ks*4 + g - 16);
    boff[ks] = (j*16 + (kb ^ (j & 7)))*8;   // u16 offset within frame
  }

  auto finalizeBone = [&](int itp){
    if (tid < FB*15){
      const int sb = itp & 1;
      const int fi = tid / 15, row = tid - fi*15;
      const float v = s_red[sb][0][fi][row] + s_red[sb][1][fi][row] +
                      s_red[sb][2][fi][row] + s_red[sb][3][fi][row] + bb2c;
      out_pbl[(F0 + (long)itp*FB + fi)*15 + row] = fmaxf(v, 0.0f);
    }
  };

  for (int it = 0; it < NIT; ++it){
    __syncthreads();                 // staged buf(it) ready; s_red[it-1] complete
    if (it > 0) finalizeBone(it - 1);
    if (it + 1 < NIT) stage((it + 1) & 1, it + 1);

    const unsigned short* fbp = s_feat[it & 1];
    const int sb = it & 1;

    // ---- bone MFMA in two 2-frame passes ----
    #pragma unroll
    for (int p = 0; p < 2; ++p){
      f32x4 ba[2][2];
      ba[0][0]=(f32x4)0.f; ba[0][1]=(f32x4)0.f; ba[1][0]=(f32x4)0.f; ba[1][1]=(f32x4)0.f;
      #pragma unroll
      for (int ks = 0; ks < 8; ++ks){
        const bf16x8 a0 = __builtin_bit_cast(bf16x8, *(const u16x8*)&fbp[(2*p+0)*JC + boff[ks]]);
        const bf16x8 a1 = __builtin_bit_cast(bf16x8, *(const u16x8*)&fbp[(2*p+1)*JC + boff[ks]]);
        ba[0][0] = __builtin_amdgcn_mfma_f32_16x16x32_bf16(a0, wb[ks][0], ba[0][0], 0, 0, 0);
        ba[0][1] = __builtin_amdgcn_mfma_f32_16x16x32_bf16(a0, wb[ks][1], ba[0][1], 0, 0, 0);
        ba[1][0] = __builtin_amdgcn_mfma_f32_16x16x32_bf16(a1, wb[ks][0], ba[1][0], 0, 0, 0);
        ba[1][1] = __builtin_amdgcn_mfma_f32_16x16x32_bf16(a1, wb[ks][1], ba[1][1], 0, 0, 0);
      }
      #pragma unroll
      for (int f2 = 0; f2 < 2; ++f2){
        float s[4] = {0.f, 0.f, 0.f, 0.f};
        #pragma unroll
        for (int nf = 0; nf < 2; ++nf)
          #pragma unroll
          for (int r = 0; r < 4; ++r)
            s[r] += gelu_fast(ba[f2][nf][r] + bb1c[nf]) * bw2c[nf];
        #pragma unroll
        for (int r = 0; r < 4; ++r){
          s[r] += __shfl_xor(s[r], 1);
          s[r] += __shfl_xor(s[r], 2);
          s[r] += __shfl_xor(s[r], 4);
          s[r] += __shfl_xor(s[r], 8);
        }
        if (c == 0)
          #pragma unroll
          for (int r = 0; r < 4; ++r) s_red[sb][w][2*p+f2][g*4 + r] = s[r];
      }
    }

    // ---- angle MFMA: wave w -> frame w, joints 0-15 ----
    {
      f32x4 acc[4];
      #pragma unroll
      for (int nf = 0; nf < 4; ++nf) acc[nf] = (f32x4)0.f;
      #pragma unroll
      for (int kt = 0; kt < 4; ++kt){
        const int kbx = kt*4 + g;
        const bf16x8 av = __builtin_bit_cast(bf16x8,
            *(const u16x8*)&fbp[w*JC + (c*16 + (kbx ^ (c & 7)))*8]);
        #pragma unroll
        for (int nf = 0; nf < 4; ++nf){
          const bf16x8 wf = __builtin_bit_cast(bf16x8,
              *(const u16x8*)&s_wa[((nf*16 + c)*16 + (kbx ^ (c & 7)))*8]);
          acc[nf] = __builtin_amdgcn_mfma_f32_16x16x32_bf16(av, wf, acc[nf], 0, 0, 0);
        }
      }
      float s[4][3];
      #pragma unroll
      for (int r = 0; r < 4; ++r){ s[r][0]=0.f; s[r][1]=0.f; s[r][2]=0.f; }
      #pragma unroll
      for (int nf = 0; nf < 4; ++nf)
        #pragma unroll
        for (int r = 0; r < 4; ++r){
          const float h = gelu_fast(acc[nf][r] + ab1c[nf]);
          s[r][0] = fmaf(h, aw2c[nf][0], s[r][0]);
          s[r][1] = fmaf(h, aw2c[nf][1], s[r][1]);
          s[r][2] = fmaf(h, aw2c[nf][2], s[r][2]);
        }
      #pragma unroll
      for (int r = 0; r < 4; ++r)
        #pragma unroll
        for (int m = 0; m < 3; ++m){
          float v = s[r][m];
          v += __shfl_xor(v, 1);
          v += __shfl_xor(v, 2);
          v += __shfl_xor(v, 4);
          v += __shfl_xor(v, 8);
          s[r][m] = v;
        }
      if (c == 0){
        const long frame = F0 + (long)it*FB + w;
        #pragma unroll
        for (int r = 0; r < 4; ++r){
          const int joint = g*4 + r;
          #pragma unroll
          for (int m = 0; m < 3; ++m)
            out_pa[(frame*NJ + joint)*3 + m] = s[r][m] + ab2c[m];
        }
      }
    }

    // ---- joint-16 angle rows (4 frames), wave 1 ----
    if (w == 1){
      f32x4 acc[4];
      #pragma unroll
      for (int nf = 0; nf < 4; ++nf) acc[nf] = (f32x4)0.f;
      #pragma unroll
      for (int kt = 0; kt < 4; ++kt){
        const int kbx = kt*4 + g;
        const bf16x8 av = __builtin_bit_cast(bf16x8,
            *(const u16x8*)&fbp[(c & 3)*JC + (256 + kbx)*8]);
        #pragma unroll
        for (int nf = 0; nf < 4; ++nf){
          const bf16x8 wf = __builtin_bit_cast(bf16x8,
              *(const u16x8*)&s_wa[((nf*16 + c)*16 + (kbx ^ (c & 7)))*8]);
          acc[nf] = __builtin_amdgcn_mfma_f32_16x16x32_bf16(av, wf, acc[nf], 0, 0, 0);
        }
      }
      float s[4][3];
      #pragma unroll
      for (int r = 0; r < 4; ++r){ s[r][0]=0.f; s[r][1]=0.f; s[r][2]=0.f; }
      #pragma unroll
      for (int nf = 0; nf < 4; ++nf)
        #pragma unroll
        for (int r = 0; r < 4; ++r){
          const float h = gelu_fast(acc[nf][r] + ab1c[nf]);
          s[r][0] = fmaf(h, aw2c[nf][0], s[r][0]);
          s[r][1] = fmaf(h, aw2c[nf][1], s[r][1]);
          s[r][2] = fmaf(h, aw2c[nf][2], s[r][2]);
        }
      #pragma unroll
      for (int r = 0; r < 4; ++r)
        #pragma unroll
        for (int m = 0; m < 3; ++m){
          float v = s[r][m];
          v += __shfl_xor(v, 1);
          v += __shfl_xor(v, 2);
          v += __shfl_xor(v, 4);
          v += __shfl_xor(v, 8);
          s[r][m] = v;
        }
      if (c == 0 && g == 0){
        #pragma unroll
        for (int r = 0; r < 4; ++r){     // r = frame within iter
          const long frame = F0 + (long)it*FB + r;
          #pragma unroll
          for (int m = 0; m < 3; ++m)
            out_pa[(frame*NJ + 16)*3 + m] = s[r][m] + ab2c[m];
        }
      }
    }
  }

  __syncthreads();
  finalizeBone(NIT - 1);
  flushMean(curb);
}

// ---------------- action classifier (reads per-batch sums) ----------------
__global__ __launch_bounds__(256) void k_action(const float* __restrict__ sum_src,
    const float* __restrict__ cw1, const float* __restrict__ cb1,
    const float* __restrict__ cw2, const float* __restrict__ cb2,
    float* __restrict__ out_lg)
{
  __shared__ float s_m[JC];
  __shared__ float s_part[4][64];
  __shared__ float s_h[64];
  const int b = blockIdx.x, tid = threadIdx.x;
  for (int i = tid; i < JC; i += 256) s_m[i] = sum_src[(long)b*JC + i] * (1.0f/243.0f);
  __syncthreads();
  const int n = tid & 63, part = tid >> 6;
  float s = 0.0f;
  const int k0 = part * 544;
  for (int k = k0; k < k0 + 544; ++k) s = fmaf(s_m[k], cw1[(long)k*64 + n], s);
  s_part[part][n] = s;
  __syncthreads();
  if (tid < 64) s_h[tid] = gelu_exact(s_part[0][tid] + s_part[1][tid] +
                                      s_part[2][tid] + s_part[3][tid] + cb1[tid]);
  __syncthreads();
  if (tid < 8){
    float v = cb2[tid];
    #pragma unroll
    for (int k = 0; k < 64; ++k) v = fmaf(s_h[k], cw2[k*8 + tid], v);
    out_lg[b*8 + tid] = v;
  }
}

extern "C" void kernel_launch(void* const* d_in, const int* in_sizes, int n_in,
                              void* d_out, int out_size, void* d_ws, size_t ws_size,
                              hipStream_t stream)
{
  const float* feat = (const float*)d_in[0];
  const float* pose = (const float*)d_in[1];
  const float* aw1  = (const float*)d_in[2];
  const float* ab1  = (const float*)d_in[3];
  const float* aw2  = (const float*)d_in[4];
  const float* ab2  = (const float*)d_in[5];
  const float* bw1  = (const float*)d_in[6];
  const float* bb1  = (const float*)d_in[7];
  const float* bw2  = (const float*)d_in[8];
  const float* bb2  = (const float*)d_in[9];
  const float* cw1  = (const float*)d_in[10];
  const float* cb1  = (const float*)d_in[11];
  const float* cw2  = (const float*)d_in[12];
  const float* cb2  = (const float*)d_in[13];

  float* out = (float*)d_out;
  float* out_pa  = out;                 // [NF,17,3]  793152
  float* out_aa  = out + 793152;        // [NF,17,1]  264384
  float* out_pbl = out + 1057536;       // [NF,15,1]  233280
  float* out_abl = out + 1290816;       // [NF,15,1]  233280
  float* out_lg  = out + 1524096;       // [64,8]     512

  float* mean_acc = (float*)d_ws;       // 64*JC f32

  k_geom<<<dim3((NF + 255)/256), dim3(256), 0, stream>>>(pose, out_aa, out_abl, mean_acc);
  k_fused<<<dim3(NF/FRB), dim3(256), 0, stream>>>(feat, aw1, ab1, aw2, ab2,
                                                  bw1, bb1, bw2, bb2,
                                                  out_pa, out_pbl, mean_acc);
  k_action<<<dim3(64), dim3(256), 0, stream>>>(mean_acc, cw1, cb1, cw2, cb2, out_lg);
}